// Round 1
// baseline (62.353 us; speedup 1.0000x reference)
//
#include <hip/hip_runtime.h>
#include <cfloat>

#define SCOPE 5
#define MASK_MAG 9999.0f
constexpr int F = 256;   // hiddenNoduleNumbers (verified from in_sizes at launch)

// ---------------------------------------------------------------------------
// K1: per-row dot products. dots[r*SCOPE+v] = data[r,:] . W[v,:]
// One wave per row (grid-strided). W staged in LDS. float4 global loads.
// ---------------------------------------------------------------------------
__global__ void dots_kernel(const float* __restrict__ data,
                            const float* __restrict__ W,
                            float* __restrict__ dots, int nrows) {
    __shared__ float wsh[SCOPE][F];
    const int tid = threadIdx.x;
    #pragma unroll
    for (int v = 0; v < SCOPE; ++v) wsh[v][tid] = W[v * F + tid];
    __syncthreads();

    const int lane = tid & 63;
    const int wid = tid >> 6;
    const int wavesPerBlock = blockDim.x >> 6;
    const int gwave = blockIdx.x * wavesPerBlock + wid;
    const int nwaves = gridDim.x * wavesPerBlock;

    for (int r = gwave; r < nrows; r += nwaves) {
        const float4 d4 = *reinterpret_cast<const float4*>(data + (size_t)r * F + lane * 4);
        float p[SCOPE];
        #pragma unroll
        for (int v = 0; v < SCOPE; ++v) {
            const float4 w4 = *reinterpret_cast<const float4*>(&wsh[v][lane * 4]);
            p[v] = d4.x * w4.x + d4.y * w4.y + d4.z * w4.z + d4.w * w4.w;
        }
        #pragma unroll
        for (int off = 32; off >= 1; off >>= 1) {
            #pragma unroll
            for (int v = 0; v < SCOPE; ++v)
                p[v] += __shfl_xor(p[v], off, 64);
        }
        if (lane == 0) {
            #pragma unroll
            for (int v = 0; v < SCOPE; ++v)
                dots[(size_t)r * SCOPE + v] = p[v];
        }
    }
}

// ---------------------------------------------------------------------------
// K2: per-batch score assembly + mask + softmax. One block (256 thr) per batch.
// score[b,t] = bias + sum_v dots[b, t+v, v]  (t+v >= T contributes 0: zero-pad)
// masked = min(score, valid ? +9999 : -9999); softmax over T; write weights.
// ---------------------------------------------------------------------------
__global__ void softmax_kernel(const float* __restrict__ dots,
                               const int* __restrict__ seq,
                               const float* __restrict__ bias,
                               float* __restrict__ wout, int T) {
    const int b = blockIdx.x;
    const int tid = threadIdx.x;
    const int lane = tid & 63, wid = tid >> 6;
    const int L = seq[b];
    const float bv = bias[0];
    const int PER = T / 256;           // 8 for T=2048
    float sc[16];
    const float* db = dots + (size_t)b * T * SCOPE;

    for (int i = 0; i < PER; ++i) {
        const int t = tid + i * 256;
        float s = bv;
        #pragma unroll
        for (int v = 0; v < SCOPE; ++v) {
            const int u = t + v;
            if (u < T) s += db[(size_t)u * SCOPE + v];
        }
        const float m = (t < L) ? MASK_MAG : -MASK_MAG;
        sc[i] = fminf(s, m);
    }

    // block max
    float mx = -FLT_MAX;
    for (int i = 0; i < PER; ++i) mx = fmaxf(mx, sc[i]);
    #pragma unroll
    for (int off = 32; off >= 1; off >>= 1) mx = fmaxf(mx, __shfl_xor(mx, off, 64));
    __shared__ float redmx[8];
    if (lane == 0) redmx[wid] = mx;
    __syncthreads();
    mx = fmaxf(fmaxf(redmx[0], redmx[1]), fmaxf(redmx[2], redmx[3]));

    // sum of exp
    float sum = 0.f;
    for (int i = 0; i < PER; ++i) { sc[i] = expf(sc[i] - mx); sum += sc[i]; }
    #pragma unroll
    for (int off = 32; off >= 1; off >>= 1) sum += __shfl_xor(sum, off, 64);
    __shared__ float redsum[8];
    if (lane == 0) redsum[wid] = sum;
    __syncthreads();
    sum = redsum[0] + redsum[1] + redsum[2] + redsum[3];
    const float inv = 1.0f / sum;

    for (int i = 0; i < PER; ++i)
        wout[(size_t)b * T + tid + i * 256] = sc[i] * inv;
}

// ---------------------------------------------------------------------------
// K3: weighted sum partials. Grid (chunks, B). Block = 256 thr = 4 waves.
// Each wave covers a quarter of the chunk's t-range; lane covers 4 f's (float4).
// Per-block LDS combine -> one partial row [F] per (b, chunk).
// ---------------------------------------------------------------------------
__global__ void wsum_kernel(const float* __restrict__ data,
                            const float* __restrict__ w,
                            float* __restrict__ partial, int T, int chunks) {
    const int b = blockIdx.y, c = blockIdx.x;
    const int tid = threadIdx.x;
    const int lane = tid & 63, wid = tid >> 6;
    const int tlen = T / chunks;     // 256 for chunks=8
    const int tw = tlen / 4;         // 64 t per wave
    const int t0 = c * tlen + wid * tw;
    const float* dBase = data + (size_t)b * T * F;
    const float* wBase = w + (size_t)b * T;

    float4 acc = make_float4(0.f, 0.f, 0.f, 0.f);
    for (int t = t0; t < t0 + tw; ++t) {
        const float wv = wBase[t];
        const float4 d4 = *reinterpret_cast<const float4*>(dBase + (size_t)t * F + lane * 4);
        acc.x += d4.x * wv; acc.y += d4.y * wv; acc.z += d4.z * wv; acc.w += d4.w * wv;
    }

    __shared__ float accs[4][F];
    *reinterpret_cast<float4*>(&accs[wid][lane * 4]) = acc;
    __syncthreads();
    const float s = accs[0][tid] + accs[1][tid] + accs[2][tid] + accs[3][tid];
    partial[((size_t)(b * chunks + c)) * F + tid] = s;
}

// ---------------------------------------------------------------------------
// K4: reduce chunk partials -> attentionResult [B, F]
// ---------------------------------------------------------------------------
__global__ void reduce_kernel(const float* __restrict__ partial,
                              float* __restrict__ out, int chunks) {
    const int b = blockIdx.x, f = threadIdx.x;
    float s = 0.f;
    for (int c = 0; c < chunks; ++c)
        s += partial[((size_t)(b * chunks + c)) * F + f];
    out[(size_t)b * F + f] = s;
}

extern "C" void kernel_launch(void* const* d_in, const int* in_sizes, int n_in,
                              void* d_out, int out_size, void* d_ws, size_t ws_size,
                              hipStream_t stream) {
    const float* data = (const float*)d_in[0];
    const int*   seq  = (const int*)d_in[1];
    const float* W    = (const float*)d_in[2];
    const float* bias = (const float*)d_in[3];

    const int B  = in_sizes[1];                 // 32
    const int Fr = in_sizes[2] / SCOPE;         // 256 (must equal F)
    const int T  = in_sizes[0] / (B * Fr);      // 2048
    (void)Fr;

    float* out_res = (float*)d_out;                      // [B, F]
    float* out_w   = (float*)d_out + (size_t)B * F;      // [B, T]

    float* dots    = (float*)d_ws;                       // B*T*SCOPE floats
    float* partial = dots + (size_t)B * T * SCOPE;       // B*chunks*F floats

    const int nrows = B * T;
    dots_kernel<<<1024, 256, 0, stream>>>(data, W, dots, nrows);
    softmax_kernel<<<B, 256, 0, stream>>>(dots, seq, bias, out_w, T);

    const int chunks = 8;
    dim3 g3(chunks, B);
    wsum_kernel<<<g3, 256, 0, stream>>>(data, out_w, partial, T, chunks);
    reduce_kernel<<<B, 256, 0, stream>>>(partial, out_res, chunks);
}

// Round 2
// 43.433 us; speedup vs baseline: 1.4356x; 1.4356x over previous
//
#include <hip/hip_runtime.h>
#include <cfloat>

#define SCOPE 5
#define MASK_MAG 9999.0f
constexpr int F = 256;     // hiddenNoduleNumbers
constexpr int TW = 32;     // t's per wave in scores kernel

// ---------------------------------------------------------------------------
// K1: sliding-window scores. scores[b,t] = bias + sum_v data[b,t+v,:] . W[v,:]
// One wave per 32 consecutive t's. 5-row register ring (float4 per lane),
// each data element loaded exactly once (+4-row halo). One butterfly per t.
// ---------------------------------------------------------------------------
__global__ __launch_bounds__(256) void scores_kernel(
    const float* __restrict__ data, const float* __restrict__ W,
    const float* __restrict__ bias, float* __restrict__ scores, int T) {
    const int b = blockIdx.y;
    const int tid = threadIdx.x;
    const int lane = tid & 63;
    const int wid = tid >> 6;
    const int lane4 = lane * 4;
    const int t0 = (blockIdx.x * 4 + wid) * TW;
    if (t0 >= T) return;
    const float* __restrict__ dBase = data + (size_t)b * T * F;
    float* __restrict__ sb = scores + (size_t)b * T;
    const float bv = bias[0];

    const float4 w0 = *(const float4*)(W + 0 * F + lane4);
    const float4 w1 = *(const float4*)(W + 1 * F + lane4);
    const float4 w2 = *(const float4*)(W + 2 * F + lane4);
    const float4 w3 = *(const float4*)(W + 3 * F + lane4);
    const float4 w4 = *(const float4*)(W + 4 * F + lane4);

    const float4 fz = make_float4(0.f, 0.f, 0.f, 0.f);
    float4 r0, r1, r2, r3, r4;

#define LOADROW(dst, u) { const int uu = (u); \
    if (uu < T) dst = *(const float4*)(dBase + (size_t)uu * F + lane4); \
    else dst = fz; }
#define DOT4(a, b) ((a).x*(b).x + (a).y*(b).y + (a).z*(b).z + (a).w*(b).w)
#define STEP(tt, A_, B_, C_, D_, E_) { \
    LOADROW(E_, (tt) + 4); \
    float s = DOT4(A_, w0) + DOT4(B_, w1) + DOT4(C_, w2) + DOT4(D_, w3) + DOT4(E_, w4); \
    s += __shfl_xor(s, 32, 64); \
    s += __shfl_xor(s, 16, 64); \
    s += __shfl_xor(s,  8, 64); \
    s += __shfl_xor(s,  4, 64); \
    s += __shfl_xor(s,  2, 64); \
    s += __shfl_xor(s,  1, 64); \
    if (lane == 0) sb[tt] = s + bv; }

    LOADROW(r0, t0); LOADROW(r1, t0 + 1); LOADROW(r2, t0 + 2); LOADROW(r3, t0 + 3);

    #pragma unroll
    for (int i = 0; i < TW - 2; i += 5) {   // 6 groups of 5 -> t0 .. t0+29
        STEP(t0 + i,     r0, r1, r2, r3, r4);
        STEP(t0 + i + 1, r1, r2, r3, r4, r0);
        STEP(t0 + i + 2, r2, r3, r4, r0, r1);
        STEP(t0 + i + 3, r3, r4, r0, r1, r2);
        STEP(t0 + i + 4, r4, r0, r1, r2, r3);
    }
    STEP(t0 + TW - 2, r0, r1, r2, r3, r4);  // t0+30
    STEP(t0 + TW - 1, r1, r2, r3, r4, r0);  // t0+31
#undef STEP
#undef DOT4
#undef LOADROW
}

// ---------------------------------------------------------------------------
// K2: per-batch mask + softmax over T. One block (256 thr) per batch.
// masked = min(score, valid ? +9999 : -9999); softmax; write weights.
// ---------------------------------------------------------------------------
__global__ __launch_bounds__(256) void softmax_kernel(
    const float* __restrict__ scores, const int* __restrict__ seq,
    float* __restrict__ wout, int T) {
    constexpr int PER = 8;                 // T = 2048 = PER * 256
    const int b = blockIdx.x;
    const int tid = threadIdx.x;
    const int lane = tid & 63, wid = tid >> 6;
    const int L = seq[b];
    const float* sb = scores + (size_t)b * T;
    float sc[PER];

    #pragma unroll
    for (int i = 0; i < PER; ++i) {
        const int t = tid + i * 256;
        const float m = (t < L) ? MASK_MAG : -MASK_MAG;
        sc[i] = fminf(sb[t], m);
    }

    float mx = -FLT_MAX;
    #pragma unroll
    for (int i = 0; i < PER; ++i) mx = fmaxf(mx, sc[i]);
    #pragma unroll
    for (int off = 32; off >= 1; off >>= 1) mx = fmaxf(mx, __shfl_xor(mx, off, 64));
    __shared__ float redmx[4];
    if (lane == 0) redmx[wid] = mx;
    __syncthreads();
    mx = fmaxf(fmaxf(redmx[0], redmx[1]), fmaxf(redmx[2], redmx[3]));

    float sum = 0.f;
    #pragma unroll
    for (int i = 0; i < PER; ++i) { sc[i] = expf(sc[i] - mx); sum += sc[i]; }
    #pragma unroll
    for (int off = 32; off >= 1; off >>= 1) sum += __shfl_xor(sum, off, 64);
    __shared__ float redsum[4];
    if (lane == 0) redsum[wid] = sum;
    __syncthreads();
    sum = redsum[0] + redsum[1] + redsum[2] + redsum[3];
    const float inv = 1.0f / sum;

    #pragma unroll
    for (int i = 0; i < PER; ++i)
        wout[(size_t)b * T + tid + i * 256] = sc[i] * inv;
}

// ---------------------------------------------------------------------------
// K3: weighted sum partials. Grid (chunks, B). Block = 256 thr = 4 waves.
// ---------------------------------------------------------------------------
__global__ __launch_bounds__(256) void wsum_kernel(
    const float* __restrict__ data, const float* __restrict__ w,
    float* __restrict__ partial, int T, int chunks) {
    const int b = blockIdx.y, c = blockIdx.x;
    const int tid = threadIdx.x;
    const int lane = tid & 63, wid = tid >> 6;
    const int tlen = T / chunks;     // 128 for chunks=16
    const int tw = tlen / 4;         // 32 t per wave
    const int t0 = c * tlen + wid * tw;
    const float* dBase = data + (size_t)b * T * F;
    const float* wBase = w + (size_t)b * T;

    float4 acc = make_float4(0.f, 0.f, 0.f, 0.f);
    for (int t = t0; t < t0 + tw; ++t) {
        const float wv = wBase[t];
        const float4 d4 = *reinterpret_cast<const float4*>(dBase + (size_t)t * F + lane * 4);
        acc.x += d4.x * wv; acc.y += d4.y * wv; acc.z += d4.z * wv; acc.w += d4.w * wv;
    }

    __shared__ float accs[4][F];
    *reinterpret_cast<float4*>(&accs[wid][lane * 4]) = acc;
    __syncthreads();
    const float s = accs[0][tid] + accs[1][tid] + accs[2][tid] + accs[3][tid];
    partial[((size_t)(b * chunks + c)) * F + tid] = s;
}

// ---------------------------------------------------------------------------
// K4: reduce chunk partials -> attentionResult [B, F]
// ---------------------------------------------------------------------------
__global__ __launch_bounds__(256) void reduce_kernel(
    const float* __restrict__ partial, float* __restrict__ out, int chunks) {
    const int b = blockIdx.x, f = threadIdx.x;
    float s = 0.f;
    for (int c = 0; c < chunks; ++c)
        s += partial[((size_t)(b * chunks + c)) * F + f];
    out[(size_t)b * F + f] = s;
}

extern "C" void kernel_launch(void* const* d_in, const int* in_sizes, int n_in,
                              void* d_out, int out_size, void* d_ws, size_t ws_size,
                              hipStream_t stream) {
    const float* data = (const float*)d_in[0];
    const int*   seq  = (const int*)d_in[1];
    const float* W    = (const float*)d_in[2];
    const float* bias = (const float*)d_in[3];

    const int B  = in_sizes[1];                 // 32
    const int Fr = in_sizes[2] / SCOPE;         // 256 (== F)
    const int T  = in_sizes[0] / (B * Fr);      // 2048
    (void)Fr;

    float* out_res = (float*)d_out;                      // [B, F]
    float* out_w   = (float*)d_out + (size_t)B * F;      // [B, T]

    float* scores  = (float*)d_ws;                       // B*T floats
    float* partial = scores + (size_t)B * T;             // B*chunks*F floats

    dim3 gS(T / (4 * TW), B);                            // (16, 32)
    scores_kernel<<<gS, 256, 0, stream>>>(data, W, bias, scores, T);
    softmax_kernel<<<B, 256, 0, stream>>>(scores, seq, out_w, T);

    const int chunks = 16;
    dim3 g3(chunks, B);
    wsum_kernel<<<g3, 256, 0, stream>>>(data, out_w, partial, T, chunks);
    reduce_kernel<<<B, 256, 0, stream>>>(partial, out_res, chunks);
}

// Round 3
// 41.940 us; speedup vs baseline: 1.4867x; 1.0356x over previous
//
#include <hip/hip_runtime.h>
#include <cfloat>

#define SCOPE 5
#define MASK_MAG 9999.0f
constexpr int F = 256;     // hiddenNoduleNumbers
constexpr int TW = 32;     // t's per wave in scores kernel

// ---------------------------------------------------------------------------
// K1: sliding-window scores. scores[b,t] = bias + sum_v data[b,t+v,:] . W[v,:]
// One wave per 32 consecutive t's. 8-row register ring (float4/lane) with
// prefetch distance 4: the row loaded at step k is first used at step k+4,
// so ~4 loads stay in flight per wave (32/CU) -> BW-bound, not latency-bound.
// ---------------------------------------------------------------------------
__global__ __launch_bounds__(256) void scores_kernel(
    const float* __restrict__ data, const float* __restrict__ W,
    const float* __restrict__ bias, float* __restrict__ scores, int T) {
    const int b = blockIdx.y;
    const int tid = threadIdx.x;
    const int lane = tid & 63;
    const int wid = tid >> 6;
    const int lane4 = lane * 4;
    const int t0 = (blockIdx.x * 4 + wid) * TW;
    if (t0 >= T) return;
    const float* __restrict__ dBase = data + (size_t)b * T * F;
    float* __restrict__ sb = scores + (size_t)b * T;
    const float bv = bias[0];

    const float4 w0 = *(const float4*)(W + 0 * F + lane4);
    const float4 w1 = *(const float4*)(W + 1 * F + lane4);
    const float4 w2 = *(const float4*)(W + 2 * F + lane4);
    const float4 w3 = *(const float4*)(W + 3 * F + lane4);
    const float4 w4 = *(const float4*)(W + 4 * F + lane4);

    const float4 fz = make_float4(0.f, 0.f, 0.f, 0.f);
    float4 s0, s1, s2, s3, s4, s5, s6, s7;

#define LOADROW(dst, u) { const int uu = (u); \
    if (uu < T) dst = *(const float4*)(dBase + (size_t)uu * F + lane4); \
    else dst = fz; }
#define DOT4(a, b) ((a).x*(b).x + (a).y*(b).y + (a).z*(b).z + (a).w*(b).w)
// step at absolute offset (i+j): dots on A..E, prefetch row i+j+8 into NEW.
#define STEP(i, j, A_, B_, C_, D_, E_, NEW_) { \
    float s = DOT4(A_, w0) + DOT4(B_, w1) + DOT4(C_, w2) + DOT4(D_, w3) + DOT4(E_, w4); \
    if ((i) + (j) < TW - 4) { LOADROW(NEW_, t0 + (i) + (j) + 8); } \
    s += __shfl_xor(s, 32, 64); \
    s += __shfl_xor(s, 16, 64); \
    s += __shfl_xor(s,  8, 64); \
    s += __shfl_xor(s,  4, 64); \
    s += __shfl_xor(s,  2, 64); \
    s += __shfl_xor(s,  1, 64); \
    if (lane == 0) sb[t0 + (i) + (j)] = s + bv; }

    // prologue: 8 independent loads in flight
    LOADROW(s0, t0 + 0); LOADROW(s1, t0 + 1); LOADROW(s2, t0 + 2); LOADROW(s3, t0 + 3);
    LOADROW(s4, t0 + 4); LOADROW(s5, t0 + 5); LOADROW(s6, t0 + 6); LOADROW(s7, t0 + 7);

    #pragma unroll
    for (int i = 0; i < TW; i += 8) {     // 4 groups of 8, all indices static
        STEP(i, 0, s0, s1, s2, s3, s4, s0);
        STEP(i, 1, s1, s2, s3, s4, s5, s1);
        STEP(i, 2, s2, s3, s4, s5, s6, s2);
        STEP(i, 3, s3, s4, s5, s6, s7, s3);
        STEP(i, 4, s4, s5, s6, s7, s0, s4);
        STEP(i, 5, s5, s6, s7, s0, s1, s5);
        STEP(i, 6, s6, s7, s0, s1, s2, s6);
        STEP(i, 7, s7, s0, s1, s2, s3, s7);
    }
#undef STEP
#undef DOT4
#undef LOADROW
}

// ---------------------------------------------------------------------------
// K2: per-batch mask + softmax over T. One block (256 thr) per batch.
// ---------------------------------------------------------------------------
__global__ __launch_bounds__(256) void softmax_kernel(
    const float* __restrict__ scores, const int* __restrict__ seq,
    float* __restrict__ wout, int T) {
    constexpr int PER = 8;                 // T = 2048 = PER * 256
    const int b = blockIdx.x;
    const int tid = threadIdx.x;
    const int lane = tid & 63, wid = tid >> 6;
    const int L = seq[b];
    const float* sb = scores + (size_t)b * T;
    float sc[PER];

    #pragma unroll
    for (int i = 0; i < PER; ++i) {
        const int t = tid + i * 256;
        const float m = (t < L) ? MASK_MAG : -MASK_MAG;
        sc[i] = fminf(sb[t], m);
    }

    float mx = -FLT_MAX;
    #pragma unroll
    for (int i = 0; i < PER; ++i) mx = fmaxf(mx, sc[i]);
    #pragma unroll
    for (int off = 32; off >= 1; off >>= 1) mx = fmaxf(mx, __shfl_xor(mx, off, 64));
    __shared__ float redmx[4];
    if (lane == 0) redmx[wid] = mx;
    __syncthreads();
    mx = fmaxf(fmaxf(redmx[0], redmx[1]), fmaxf(redmx[2], redmx[3]));

    float sum = 0.f;
    #pragma unroll
    for (int i = 0; i < PER; ++i) { sc[i] = expf(sc[i] - mx); sum += sc[i]; }
    #pragma unroll
    for (int off = 32; off >= 1; off >>= 1) sum += __shfl_xor(sum, off, 64);
    __shared__ float redsum[4];
    if (lane == 0) redsum[wid] = sum;
    __syncthreads();
    sum = redsum[0] + redsum[1] + redsum[2] + redsum[3];
    const float inv = 1.0f / sum;

    #pragma unroll
    for (int i = 0; i < PER; ++i)
        wout[(size_t)b * T + tid + i * 256] = sc[i] * inv;
}

// ---------------------------------------------------------------------------
// K3: weighted sum partials. Grid (chunks=32, B). Block = 256 thr = 4 waves.
// Unrolled x4 with 4 independent accumulators + float4 weight loads.
// ---------------------------------------------------------------------------
__global__ __launch_bounds__(256) void wsum_kernel(
    const float* __restrict__ data, const float* __restrict__ w,
    float* __restrict__ partial, int T, int chunks) {
    const int b = blockIdx.y, c = blockIdx.x;
    const int tid = threadIdx.x;
    const int lane = tid & 63, wid = tid >> 6;
    const int tlen = T / chunks;     // 64 for chunks=32
    const int tw = tlen / 4;         // 16 t per wave
    const int t0 = c * tlen + wid * tw;
    const float* dBase = data + (size_t)b * T * F;
    const float* wBase = w + (size_t)b * T;
    const int lane4 = lane * 4;

    float4 a0 = make_float4(0.f, 0.f, 0.f, 0.f);
    float4 a1 = a0, a2 = a0, a3 = a0;
    for (int t = t0; t < t0 + tw; t += 4) {
        const float4 wv = *reinterpret_cast<const float4*>(wBase + t);
        const float4 d0 = *reinterpret_cast<const float4*>(dBase + (size_t)(t + 0) * F + lane4);
        const float4 d1 = *reinterpret_cast<const float4*>(dBase + (size_t)(t + 1) * F + lane4);
        const float4 d2 = *reinterpret_cast<const float4*>(dBase + (size_t)(t + 2) * F + lane4);
        const float4 d3 = *reinterpret_cast<const float4*>(dBase + (size_t)(t + 3) * F + lane4);
        a0.x += d0.x * wv.x; a0.y += d0.y * wv.x; a0.z += d0.z * wv.x; a0.w += d0.w * wv.x;
        a1.x += d1.x * wv.y; a1.y += d1.y * wv.y; a1.z += d1.z * wv.y; a1.w += d1.w * wv.y;
        a2.x += d2.x * wv.z; a2.y += d2.y * wv.z; a2.z += d2.z * wv.z; a2.w += d2.w * wv.z;
        a3.x += d3.x * wv.w; a3.y += d3.y * wv.w; a3.z += d3.z * wv.w; a3.w += d3.w * wv.w;
    }
    float4 acc;
    acc.x = (a0.x + a1.x) + (a2.x + a3.x);
    acc.y = (a0.y + a1.y) + (a2.y + a3.y);
    acc.z = (a0.z + a1.z) + (a2.z + a3.z);
    acc.w = (a0.w + a1.w) + (a2.w + a3.w);

    __shared__ float accs[4][F];
    *reinterpret_cast<float4*>(&accs[wid][lane4]) = acc;
    __syncthreads();
    const float s = accs[0][tid] + accs[1][tid] + accs[2][tid] + accs[3][tid];
    partial[((size_t)(b * chunks + c)) * F + tid] = s;
}

// ---------------------------------------------------------------------------
// K4: reduce chunk partials -> attentionResult [B, F]
// ---------------------------------------------------------------------------
__global__ __launch_bounds__(256) void reduce_kernel(
    const float* __restrict__ partial, float* __restrict__ out, int chunks) {
    const int b = blockIdx.x, f = threadIdx.x;
    float s = 0.f;
    for (int c = 0; c < chunks; ++c)
        s += partial[((size_t)(b * chunks + c)) * F + f];
    out[(size_t)b * F + f] = s;
}

extern "C" void kernel_launch(void* const* d_in, const int* in_sizes, int n_in,
                              void* d_out, int out_size, void* d_ws, size_t ws_size,
                              hipStream_t stream) {
    const float* data = (const float*)d_in[0];
    const int*   seq  = (const int*)d_in[1];
    const float* W    = (const float*)d_in[2];
    const float* bias = (const float*)d_in[3];

    const int B  = in_sizes[1];                 // 32
    const int Fr = in_sizes[2] / SCOPE;         // 256 (== F)
    const int T  = in_sizes[0] / (B * Fr);      // 2048
    (void)Fr;

    float* out_res = (float*)d_out;                      // [B, F]
    float* out_w   = (float*)d_out + (size_t)B * F;      // [B, T]

    float* scores  = (float*)d_ws;                       // B*T floats
    float* partial = scores + (size_t)B * T;             // B*chunks*F floats

    dim3 gS(T / (4 * TW), B);                            // (16, 32)
    scores_kernel<<<gS, 256, 0, stream>>>(data, W, bias, scores, T);
    softmax_kernel<<<B, 256, 0, stream>>>(scores, seq, out_w, T);

    const int chunks = 32;
    dim3 g3(chunks, B);
    wsum_kernel<<<g3, 256, 0, stream>>>(data, out_w, partial, T, chunks);
    reduce_kernel<<<B, 256, 0, stream>>>(partial, out_res, chunks);
}

// Round 4
// 35.373 us; speedup vs baseline: 1.7627x; 1.1856x over previous
//
#include <hip/hip_runtime.h>
#include <cfloat>

#define SCOPE 5
#define MASK_MAG 9999.0f
constexpr int F = 256;     // hiddenNoduleNumbers
constexpr int TW = 32;     // t's per wave
constexpr int WAVES = 4;   // waves per block

// ---------------------------------------------------------------------------
// K1: fused sliding-window scores + online-softmax weighted accumulation.
// One wave per 32 t's. 16-slot register ring of rows (float4/lane). Each data
// row is loaded from HBM exactly once: used by 5 sliding dots AND by the
// p[t]*row accumulation. Online softmax in groups of 8 (one rescale/group).
// Emits raw scores (for the weight output) + per-wave (m, s, acc[Fchunk]).
// Ring liveness: slots 0..7 hold rows tb..tb+7, slots 8..15 rows tb+8..tb+15.
// After group A's acc (rows tb..tb+7 dead) prefetch rows tb+16..23 -> slots
// 0..7; after group B's acc prefetch rows tb+24..31 -> slots 8..15. Prefetch
// is consumed >=4 steps after issue.
// ---------------------------------------------------------------------------
__global__ __launch_bounds__(256) void fused_kernel(
    const float* __restrict__ data, const float* __restrict__ W,
    const float* __restrict__ bias, const int* __restrict__ seq,
    float* __restrict__ scores, float* __restrict__ pacc,
    float* __restrict__ pm, float* __restrict__ ps, int T) {
    const int b = blockIdx.y;
    const int tid = threadIdx.x;
    const int lane = tid & 63;
    const int wid = tid >> 6;
    const int lane4 = lane * 4;
    const int widx = blockIdx.x * WAVES + wid;     // wave index within batch b
    const int t0 = widx * TW;
    if (t0 >= T) return;
    const int npw = T / TW;
    const float* __restrict__ dBase = data + (size_t)b * T * F;
    float* __restrict__ sb = scores + (size_t)b * T;
    const float bv = bias[0];
    const int L = seq[b];

    float4 w[SCOPE];
    #pragma unroll
    for (int v = 0; v < SCOPE; ++v)
        w[v] = *(const float4*)(W + v * F + lane4);

    const float4 fz = make_float4(0.f, 0.f, 0.f, 0.f);
    float4 S[16];

#define LOADROW(slot, off) do { \
    if ((off) < TW + 4) { \
        const int uu = t0 + (off); \
        S[slot] = (uu < T) ? *(const float4*)(dBase + (size_t)uu * F + lane4) : fz; \
    } } while (0)
#define DOT4(a, b) ((a).x*(b).x + (a).y*(b).y + (a).z*(b).z + (a).w*(b).w)

    // prologue: 16 rows in flight
    #pragma unroll
    for (int k = 0; k < 16; ++k) LOADROW(k, k);

    float m_run = -FLT_MAX, s_run = 0.f;
    float4 acc = fz;

    #pragma unroll
    for (int ii = 0; ii < 2; ++ii) {
        const int base = ii * 16;
        float sc[8];

        // ---- group A: t = t0+base .. +7, dots use slots j..j+4 ----
        #pragma unroll
        for (int j = 0; j < 8; ++j) {
            float s = DOT4(S[j], w[0]) + DOT4(S[j+1], w[1]) + DOT4(S[j+2], w[2])
                    + DOT4(S[j+3], w[3]) + DOT4(S[j+4], w[4]);
            s += __shfl_xor(s, 32, 64);
            s += __shfl_xor(s, 16, 64);
            s += __shfl_xor(s,  8, 64);
            s += __shfl_xor(s,  4, 64);
            s += __shfl_xor(s,  2, 64);
            s += __shfl_xor(s,  1, 64);
            s += bv;
            const int t = t0 + base + j;
            if (lane == 0) sb[t] = s;
            sc[j] = fminf(s, (t < L) ? MASK_MAG : -MASK_MAG);
        }
        // online update A (rows in slots 0..7)
        {
            float gm = fmaxf(fmaxf(fmaxf(sc[0], sc[1]), fmaxf(sc[2], sc[3])),
                             fmaxf(fmaxf(sc[4], sc[5]), fmaxf(sc[6], sc[7])));
            const float m_new = fmaxf(m_run, gm);
            const float corr = expf(m_run - m_new);
            float psum = 0.f; float4 ga = fz;
            #pragma unroll
            for (int j = 0; j < 8; ++j) {
                const float p = expf(sc[j] - m_new);
                psum += p;
                ga.x += p * S[j].x; ga.y += p * S[j].y;
                ga.z += p * S[j].z; ga.w += p * S[j].w;
            }
            s_run = s_run * corr + psum;
            acc.x = acc.x * corr + ga.x; acc.y = acc.y * corr + ga.y;
            acc.z = acc.z * corr + ga.z; acc.w = acc.w * corr + ga.w;
            m_run = m_new;
        }
        // prefetch rows tb+16..23 into dead slots 0..7
        #pragma unroll
        for (int k = 0; k < 8; ++k) LOADROW(k, base + 16 + k);

        // ---- group B: t = t0+base+8 .. +15, dots use slots (j..j+4)&15 ----
        #pragma unroll
        for (int j = 8; j < 16; ++j) {
            float s = DOT4(S[j & 15], w[0]) + DOT4(S[(j+1) & 15], w[1])
                    + DOT4(S[(j+2) & 15], w[2]) + DOT4(S[(j+3) & 15], w[3])
                    + DOT4(S[(j+4) & 15], w[4]);
            s += __shfl_xor(s, 32, 64);
            s += __shfl_xor(s, 16, 64);
            s += __shfl_xor(s,  8, 64);
            s += __shfl_xor(s,  4, 64);
            s += __shfl_xor(s,  2, 64);
            s += __shfl_xor(s,  1, 64);
            s += bv;
            const int t = t0 + base + j;
            if (lane == 0) sb[t] = s;
            sc[j - 8] = fminf(s, (t < L) ? MASK_MAG : -MASK_MAG);
        }
        // online update B (rows in slots 8..15)
        {
            float gm = fmaxf(fmaxf(fmaxf(sc[0], sc[1]), fmaxf(sc[2], sc[3])),
                             fmaxf(fmaxf(sc[4], sc[5]), fmaxf(sc[6], sc[7])));
            const float m_new = fmaxf(m_run, gm);
            const float corr = expf(m_run - m_new);
            float psum = 0.f; float4 ga = fz;
            #pragma unroll
            for (int j = 0; j < 8; ++j) {
                const float p = expf(sc[j] - m_new);
                psum += p;
                ga.x += p * S[8 + j].x; ga.y += p * S[8 + j].y;
                ga.z += p * S[8 + j].z; ga.w += p * S[8 + j].w;
            }
            s_run = s_run * corr + psum;
            acc.x = acc.x * corr + ga.x; acc.y = acc.y * corr + ga.y;
            acc.z = acc.z * corr + ga.z; acc.w = acc.w * corr + ga.w;
            m_run = m_new;
        }
        // prefetch rows tb+24..31 into dead slots 8..15
        #pragma unroll
        for (int k = 0; k < 8; ++k) LOADROW(8 + k, base + 24 + k);
    }
#undef DOT4
#undef LOADROW

    // per-wave partials
    const int pw = b * npw + widx;
    *reinterpret_cast<float4*>(pacc + (size_t)pw * F + lane4) = acc;
    if (lane == 0) { pm[pw] = m_run; ps[pw] = s_run; }
}

// ---------------------------------------------------------------------------
// K2: per-batch combine. Reduce npw=64 wave partials with exp(m_i - M)
// rescale -> attentionResult; recompute weights from raw scores.
// ---------------------------------------------------------------------------
__global__ __launch_bounds__(256) void finalize_kernel(
    const float* __restrict__ scores, const float* __restrict__ pacc,
    const float* __restrict__ pm, const float* __restrict__ ps,
    const int* __restrict__ seq, float* __restrict__ out_res,
    float* __restrict__ out_w, int T, int npw) {
    const int b = blockIdx.x;
    const int tid = threadIdx.x;
    __shared__ float scale[64];
    __shared__ float MS[2];

    if (tid < 64) {
        const float m = pm[b * npw + tid];
        const float s = ps[b * npw + tid];
        float M = m;
        #pragma unroll
        for (int off = 32; off >= 1; off >>= 1) M = fmaxf(M, __shfl_xor(M, off, 64));
        const float e = expf(m - M);
        float se = e * s;
        #pragma unroll
        for (int off = 32; off >= 1; off >>= 1) se += __shfl_xor(se, off, 64);
        scale[tid] = e;
        if (tid == 0) { MS[0] = M; MS[1] = 1.0f / se; }
    }
    __syncthreads();
    const float M = MS[0], invS = MS[1];

    // attentionResult: thread tid owns feature f = tid
    float o = 0.f;
    for (int i = 0; i < npw; ++i)
        o += scale[i] * pacc[((size_t)(b * npw + i)) * F + tid];
    out_res[(size_t)b * F + tid] = o * invS;

    // attentionWeight from raw scores
    const int L = seq[b];
    for (int t = tid; t < T; t += 256) {
        const float raw = scores[(size_t)b * T + t];
        const float msk = fminf(raw, (t < L) ? MASK_MAG : -MASK_MAG);
        out_w[(size_t)b * T + t] = expf(msk - M) * invS;
    }
}

extern "C" void kernel_launch(void* const* d_in, const int* in_sizes, int n_in,
                              void* d_out, int out_size, void* d_ws, size_t ws_size,
                              hipStream_t stream) {
    const float* data = (const float*)d_in[0];
    const int*   seq  = (const int*)d_in[1];
    const float* W    = (const float*)d_in[2];
    const float* bias = (const float*)d_in[3];

    const int B  = in_sizes[1];                 // 32
    const int Fr = in_sizes[2] / SCOPE;         // 256 (== F)
    const int T  = in_sizes[0] / (B * Fr);      // 2048
    (void)Fr;
    const int npw = T / TW;                     // 64 wave-partials per batch

    float* out_res = (float*)d_out;                      // [B, F]
    float* out_w   = (float*)d_out + (size_t)B * F;      // [B, T]

    float* scores = (float*)d_ws;                        // B*T
    float* pacc   = scores + (size_t)B * T;              // B*npw*F
    float* pm     = pacc + (size_t)B * npw * F;          // B*npw
    float* ps     = pm + (size_t)B * npw;                // B*npw

    dim3 g1(T / (WAVES * TW), B);                        // (16, 32)
    fused_kernel<<<g1, 256, 0, stream>>>(data, W, bias, seq, scores, pacc, pm, ps, T);
    finalize_kernel<<<B, 256, 0, stream>>>(scores, pacc, pm, ps, seq, out_res, out_w, T, npw);
}